// Round 8
// baseline (584.510 us; speedup 1.0000x reference)
//
#include <hip/hip_runtime.h>
#include <math.h>

#define DEVI static __device__ __forceinline__

constexpr int Bn = 4, Cn = 4, Pn = 16384, Sn = 8192, Kn = 16;
constexpr float GN_N = 131072.0f;   // S*K per (b,channel)
constexpr int PART_STRIDE = 96;     // 79 used
constexpr int ST_CHUNKS = 128;      // k_stats grid.x
constexpr int TILE = 512;           // k_topk candidate tile

typedef __attribute__((ext_vector_type(8))) short s16x8;
typedef __attribute__((ext_vector_type(4))) float f32x4;

// non-contracted f32 ops (exact pd must match np's mul/add order)
DEVI float mulrn(float a, float b){ return __fmul_rn(a, b); }
DEVI float addrn(float a, float b){ return __fadd_rn(a, b); }
DEVI float subrn(float a, float b){ return __fsub_rn(a, b); }
DEVI float leaky(float v, float s){ return v >= 0.0f ? v : s * v; }

// DPP row_shr:1 == shfl_up(x,1,16) within each 16-lane quarter (DPP row).
DEVI float dpp_up1f(float x){
  int xi = __builtin_bit_cast(int, x);
  int r = __builtin_amdgcn_update_dpp(xi, xi, 0x111, 0xF, 0xF, false);
  return __builtin_bit_cast(float, r);
}
DEVI int dpp_up1i(int x){
  return __builtin_amdgcn_update_dpp(x, x, 0x111, 0xF, 0xF, false);
}
// lane (i|15) broadcast within each 16-lane quarter
DEVI float swz15(float x){
  int xi = __builtin_bit_cast(int, x);
  int r = __builtin_amdgcn_ds_swizzle(xi, 0x1FF);
  return __builtin_bit_cast(float, r);
}

// bf16 RN hi/lo split: v ~= hi + lo with |v-hi-lo| <= 2^-18|v|
DEVI void bsplit(float v, unsigned &hi, unsigned &lo){
  unsigned u = __builtin_bit_cast(unsigned, v);
  hi = (u + 0x7FFFu + ((u >> 16) & 1u)) >> 16;
  float fh = __builtin_bit_cast(float, hi << 16);
  float r = v - fh;
  unsigned u2 = __builtin_bit_cast(unsigned, r);
  lo = (u2 + 0x7FFFu + ((u2 >> 16) & 1u)) >> 16;
}

// ---------------- K1: pack coords + norm (f32) + bf16 hi/lo B-record -------
// B-record (32B = 16 bf16, K-slots 0..15):
// [vhx,vhy,vhz, vhx,vhy,vhz, vlx,vly] [vlz, -wh, -wl, vlx,vly,vlz, 0,0]
__global__ void k_pack(const float* __restrict__ x, float4* __restrict__ pk,
                       uint4* __restrict__ rec){
  int i = blockIdx.x * 256 + threadIdx.x;       // 0 .. B*P-1
  int b = i >> 14, p = i & (Pn - 1);
  const float* xb = x + (size_t)b * Cn * Pn;
  float x0 = xb[p], x1 = xb[Pn + p], x2 = xb[2 * Pn + p];
  float n = addrn(addrn(mulrn(x0, x0), mulrn(x1, x1)), mulrn(x2, x2));
  pk[i] = make_float4(x0, x1, x2, n);
  unsigned hx, lx, hy, ly, hz, lz, hw, lw;
  bsplit(x0, hx, lx); bsplit(x1, hy, ly); bsplit(x2, hz, lz); bsplit(n, hw, lw);
  unsigned nwh = hw ^ 0x8000u, nwl = lw ^ 0x8000u;   // negate bf16 (exact)
  uint4 r0 = { hx | (hy << 16), hz | (hx << 16), hy | (hz << 16), lx | (ly << 16) };
  uint4 r1 = { lz | (nwh << 16), nwl | (lx << 16), ly | (lz << 16), 0u };
  rec[i * 2] = r0; rec[i * 2 + 1] = r1;
}

// ---------------- K1b: per-query A-record (32B = 16 bf16) ------------------
// [2shx,2shy,2shz, 2slx,2sly,2slz, 2shx,2shy] [2shz, 1, 1, 2slx,2sly,2slz, 0,0]
__global__ void k_aq(const float4* __restrict__ pk, const int* __restrict__ perm,
                     uint4* __restrict__ aq){
  int i = blockIdx.x * 256 + threadIdx.x;       // 0 .. B*Sn-1
  int b = i >> 13;
  int q = perm[i];
  float4 sv = pk[b * Pn + q];
  float tx = 2.0f * sv.x, ty = 2.0f * sv.y, tz = 2.0f * sv.z;
  unsigned thx, tlx, thy, tly, thz, tlz;
  bsplit(tx, thx, tlx); bsplit(ty, thy, tly); bsplit(tz, thz, tlz);
  const unsigned one = 0x3F80u;
  uint4 a0 = { thx | (thy << 16), thz | (tlx << 16), tly | (tlz << 16), thx | (thy << 16) };
  uint4 a1 = { thz | (one << 16), one | (tlx << 16), tly | (tlz << 16), 0u };
  aq[i * 2] = a0; aq[i * 2 + 1] = a1;
}

// ---------------- K2: stable top-16 per (b,s) via MFMA screen --------------
// Block 256 = 4 waves; wave = 16 queries (one per C-row), quarter h owns
// queries 4h..4h+3 (C rows) and runs the DPP insert machinery for them.
// Screen: mfma_f32_16x16x32_bf16 with hi/lo-split operands (full 4-term
// product + w hi/lo in K-slots) -> |screen - exact| <= ~5e-3; slack 1e-2.
// Insert path recomputes EXACT np-order pd from f32 coords in LDS.
__launch_bounds__(256, 2)
__global__ void k_topk(const float4* __restrict__ pk, const uint4* __restrict__ rec,
                       const uint4* __restrict__ aq, const int* __restrict__ perm,
                       int* __restrict__ idx){
  __shared__ uint4 lbuf[TILE * 2 + 1];          // B-records + 16B zero pad
  __shared__ float4 lpk[TILE];                  // exact coords for insert path
  const int b = blockIdx.y;
  const int tid = threadIdx.x;
  const int lane = tid & 63;
  const int lane16 = lane & 15;
  const int h = lane >> 4;                      // quarter
  const int w = tid >> 6;                       // wave in block
  const bool lane0 = (lane16 == 0);
  const unsigned long long qmask = 0xFFFFull << (h * 16);
  const int qbase = (blockIdx.x * 4 + w) * 16;  // this wave's 16 queries

  // A-frag: lane holds A[row=lane16][k=8h..8h+7]; quarters 2,3 are zero slots.
  s16x8 afrag = (s16x8){0,0,0,0,0,0,0,0};
  if (h < 2)
    afrag = __builtin_bit_cast(s16x8, aq[(b * Sn + qbase + lane16) * 2 + h]);

  // exact query coords for this quarter's 4 queries
  float qx[4], qy[4], qz[4], qn[4];
#pragma unroll
  for (int r = 0; r < 4; ++r){
    int q = perm[b * Sn + qbase + 4 * h + r];
    float4 sv = pk[b * Pn + q];
    qx[r] = sv.x; qy[r] = sv.y; qz[r] = sv.z; qn[r] = sv.w;
  }

  float lv[4] = {-INFINITY, -INFINITY, -INFINITY, -INFINITY};
  int   li[4] = {0, 0, 0, 0};
  float T[4]  = {-INFINITY, -INFINITY, -INFINITY, -INFINITY};

  const int boff = lane16 * 2 + h;              // rec sub-index (h<2)
  const bool bvalid = (h < 2);

#define PROC(REG, M, CB16)                                                    \
  { unsigned long long mm = __ballot(C[M][REG] > T[REG]) & qmask;             \
    if (mm){                                                                  \
      do {                                                                    \
        const int src = __builtin_ctzll(mm);                                  \
        mm &= mm - 1;                                                         \
        const int lc = (CB16) + (src & 15);                                   \
        const float4 cd = lpk[lc];                                            \
        const float dot = addrn(addrn(mulrn(cd.x, qx[REG]),                   \
                                      mulrn(cd.y, qy[REG])),                  \
                                mulrn(cd.z, qz[REG]));                        \
        const float cv = subrn(subrn(mulrn(2.0f, dot), cd.w), qn[REG]);       \
        const int ci = gbase + lc;                                            \
        const float upv = dpp_up1f(lv[REG]);                                  \
        const int   upi = dpp_up1i(li[REG]);                                  \
        const bool keep = (lv[REG] >= cv);                                    \
        const bool ins  = (!keep) && (lane0 || upv >= cv);                    \
        lv[REG] = keep ? lv[REG] : (ins ? cv : upv);                          \
        li[REG] = keep ? li[REG] : (ins ? ci : upi);                          \
      } while (mm);                                                           \
      const float tau = swz15(lv[REG]);                                       \
      T[REG] = subrn(addrn(tau, qn[REG]),                                     \
                     fmaf(fabsf(tau) + fabsf(qn[REG]), 1e-6f, 1e-2f));        \
    } }

  for (int tile = 0; tile < Pn / TILE; ++tile){
    __syncthreads();
    const uint4* grec = rec + (size_t)(b * Pn + tile * TILE) * 2;
    for (int j = tid; j < TILE * 2; j += 256) lbuf[j] = grec[j];
    const float4* gpk = pk + b * Pn + tile * TILE;
    for (int j = tid; j < TILE; j += 256) lpk[j] = gpk[j];
    if (tid == 0) lbuf[TILE * 2] = (uint4){0u, 0u, 0u, 0u};
    __syncthreads();
    const int gbase = tile * TILE;

    for (int st = 0; st < TILE / 64; ++st){
      const int cb = st * 64;
      f32x4 C[4];
#pragma unroll
      for (int m = 0; m < 4; ++m){
        const int bidx = bvalid ? (cb * 2 + m * 32 + boff) : (TILE * 2);
        s16x8 bfrag = __builtin_bit_cast(s16x8, lbuf[bidx]);
        C[m] = __builtin_amdgcn_mfma_f32_16x16x32_bf16(
                 afrag, bfrag, (f32x4){0.f, 0.f, 0.f, 0.f}, 0, 0, 0);
      }
      float mxr[4], anyd;
#pragma unroll
      for (int reg = 0; reg < 4; ++reg){
        float mx = fmaxf(fmaxf(C[0][reg], C[1][reg]),
                         fmaxf(C[2][reg], C[3][reg]));
        mxr[reg] = mx;
        float dd = mx - T[reg];
        anyd = (reg == 0) ? dd : fmaxf(anyd, dd);
      }
      if (__ballot(anyd > 0.f)){
#pragma unroll
        for (int reg = 0; reg < 4; ++reg){
          if (__ballot(mxr[reg] > T[reg]) & qmask){
            PROC(reg, 0, cb)
            PROC(reg, 1, cb + 16)
            PROC(reg, 2, cb + 32)
            PROC(reg, 3, cb + 48)
          }
        }
      }
    }
  }
#undef PROC
#pragma unroll
  for (int reg = 0; reg < 4; ++reg)
    idx[(b * Sn + qbase + 4 * h + reg) * Kn + lane16] = li[reg];
}

// scramble: x1[b,c,s',k'] = x[b,c, idx[b, (16s'+k') & 8191, (16s'+k') >> 13]]
DEVI int idxq(const int* __restrict__ idxb, int f){
  return idxb[(f & (Sn - 1)) * Kn + (f >> 13)];
}

DEVI float wred(float v){
  v += __shfl_down(v, 32); v += __shfl_down(v, 16); v += __shfl_down(v, 8);
  v += __shfl_down(v, 4);  v += __shfl_down(v, 2);  v += __shfl_down(v, 1);
  return v;
}

// ---------------- K3: GN moment accumulation ----------------
// grid (128, B), block 256: thread -> (sp, kq); sp = chunk*64 + tid>>2, 4 k's.
__global__ void k_stats(const float4* __restrict__ pk, const float* __restrict__ x,
                        const int* __restrict__ idx, float* __restrict__ part){
  const int b = blockIdx.y, chunk = blockIdx.x, tid = threadIdx.x;
  const int sp = chunk * 64 + (tid >> 2);
  const int kq = tid & 3;
  const int* idxb = idx + b * Sn * Kn;
  const float* xw = x + ((size_t)b * Cn + 3) * Pn;

  float M10[55], mu10[10], M4[10], mu4[4];
#pragma unroll
  for (int i = 0; i < 55; ++i) M10[i] = 0.f;
#pragma unroll
  for (int i = 0; i < 10; ++i){ mu10[i] = 0.f; M4[i] = 0.f; }
#pragma unroll
  for (int i = 0; i < 4; ++i) mu4[i] = 0.f;

  const int qc = idxq(idxb, sp * 16);
  const float4 cv = pk[b * Pn + qc];

#pragma unroll
  for (int kk = 0; kk < 4; ++kk){
    const int k = kq * 4 + kk;
    const int qn = idxq(idxb, sp * 16 + k);
    const float4 pv = pk[b * Pn + qn];
    const float pw = xw[qn];
    const float dx = subrn(pv.x, cv.x), dy = subrn(pv.y, cv.y), dz = subrn(pv.z, cv.z);
    const float temp = sqrtf(addrn(addrn(mulrn(dx, dx), mulrn(dy, dy)), mulrn(dz, dz)));
    const float E[10] = {pv.x, pv.y, pv.z, cv.x, cv.y, cv.z, dx, dy, dz, temp};
    const float X[4]  = {pv.x, pv.y, pv.z, pw};
    int c = 0;
#pragma unroll
    for (int i = 0; i < 10; ++i){
      mu10[i] += E[i];
#pragma unroll
      for (int j = i; j < 10; ++j){ M10[c] += E[i] * E[j]; ++c; }
    }
    c = 0;
#pragma unroll
    for (int i = 0; i < 4; ++i){
      mu4[i] += X[i];
#pragma unroll
      for (int j = i; j < 4; ++j){ M4[c] += X[i] * X[j]; ++c; }
    }
  }

  __shared__ float red[4][80];
  const int wid = tid >> 6, ln = tid & 63;
#pragma unroll
  for (int i = 0; i < 55; ++i){ float v = wred(M10[i]); if (ln == 0) red[wid][i] = v; }
#pragma unroll
  for (int i = 0; i < 10; ++i){ float v = wred(mu10[i]); if (ln == 0) red[wid][55 + i] = v; }
#pragma unroll
  for (int i = 0; i < 10; ++i){ float v = wred(M4[i]); if (ln == 0) red[wid][65 + i] = v; }
#pragma unroll
  for (int i = 0; i < 4; ++i){ float v = wred(mu4[i]); if (ln == 0) red[wid][75 + i] = v; }
  __syncthreads();
  if (tid < 79){
    float sum = ((red[0][tid] + red[1][tid]) + red[2][tid]) + red[3][tid];
    part[(b * ST_CHUNKS + chunk) * PART_STRIDE + tid] = sum;
  }
}

// ---------------- K4: fold moments into per-(b,ch) scale/shift ----------------
__global__ void k_stats2(const float* __restrict__ part,
                         const float* __restrict__ pos_w, const float* __restrict__ conv_w,
                         const float* __restrict__ bn2_g, const float* __restrict__ bn2_b,
                         const float* __restrict__ bn_g,  const float* __restrict__ bn_b,
                         float2* __restrict__ stats){
  __shared__ float phalf[8][80];
  __shared__ float sacc[4][80];
  const int t = threadIdx.x;
  if (t < 640){
    const int pair = t / 80, i = t % 80;      // pair = b*2 + half
    if (i < 79){
      const int bb = pair >> 1, half = pair & 1;
      float a = 0.f;
      for (int c = half * 64; c < half * 64 + 64; ++c)
        a += part[(bb * ST_CHUNKS + c) * PART_STRIDE + i];
      phalf[pair][i] = a;
    }
  }
  __syncthreads();
  if (t < 320){
    const int bb = t / 80, i = t % 80;
    if (i < 79) sacc[bb][i] = phalf[bb * 2][i] + phalf[bb * 2 + 1][i];
  }
  __syncthreads();
  if (t >= 256) return;
  const int b = t >> 6, o = t & 63;
  const float* acc = sacc[b];
  float mean, ex2, gamma, beta;
  if (o < 32){                        // xc channels: conv path, bn_g/bn_b
    const float* w = conv_w + o * 4;
    float m = 0.f, e2 = 0.f; int id = 0;
#pragma unroll
    for (int i = 0; i < 4; ++i){
      m += w[i] * acc[75 + i];
#pragma unroll
      for (int j = i; j < 4; ++j){
        float t2 = w[i] * w[j] * acc[65 + id];
        e2 += (i == j) ? t2 : 2.0f * t2; ++id;
      }
    }
    mean = m / GN_N; ex2 = e2 / GN_N; gamma = bn_g[o]; beta = bn_b[o];
  } else {                            // pe channels: pos path, bn2_g/bn2_b
    const float* w = pos_w + (o - 32) * 10;
    float m = 0.f, e2 = 0.f; int id = 0;
#pragma unroll
    for (int i = 0; i < 10; ++i){
      m += w[i] * acc[55 + i];
#pragma unroll
      for (int j = i; j < 10; ++j){
        float t2 = w[i] * w[j] * acc[id];
        e2 += (i == j) ? t2 : 2.0f * t2; ++id;
      }
    }
    mean = m / GN_N; ex2 = e2 / GN_N; gamma = bn2_g[o - 32]; beta = bn2_b[o - 32];
  }
  const float var = fmaxf(ex2 - mean * mean, 0.f);
  const float rstd = 1.0f / sqrtf(var + 1e-5f);
  const float scale = rstd * gamma;
  stats[b * 64 + o] = make_float2(scale, beta - mean * scale);
}

// ---------------- K5: fused features + attention + output ----------------
__global__ void k_final(const float4* __restrict__ pk, const float* __restrict__ x,
                        const int* __restrict__ idx, const float2* __restrict__ stats,
                        const float* __restrict__ conv_w, const float* __restrict__ pos_w,
                        const float* __restrict__ att_w1, const float* __restrict__ att_w2,
                        const float* __restrict__ b1_w, const float* __restrict__ b2_w,
                        float* __restrict__ out){
  const int b = blockIdx.y;
  const int tid = threadIdx.x;
  const int k = tid & 15;
  const int sp = blockIdx.x * 16 + (tid >> 4);
  const int* idxb = idx + b * Sn * Kn;
  const float* xw = x + ((size_t)b * Cn + 3) * Pn;

  const int qn = idxq(idxb, sp * 16 + k);
  const float4 pv = pk[b * Pn + qn];
  const float pw = xw[qn];
  const float cx = __shfl(pv.x, 0, 16), cy = __shfl(pv.y, 0, 16);
  const float cz = __shfl(pv.z, 0, 16), cw = __shfl(pw, 0, 16);
  const float dx = subrn(pv.x, cx), dy = subrn(pv.y, cy), dz = subrn(pv.z, cz);
  const float temp = sqrtf(addrn(addrn(mulrn(dx, dx), mulrn(dy, dy)), mulrn(dz, dz)));
  const float E[10]  = {pv.x, pv.y, pv.z, cx, cy, cz, dx, dy, dz, temp};
  const float X4[4]  = {pv.x, pv.y, pv.z, pw};
  const float2* stb = stats + b * 64;

  float feat[64];
  for (int o = 0; o < 32; ++o){       // xc
    float v = 0.f;
#pragma unroll
    for (int c = 0; c < 4; ++c) v = fmaf(conv_w[o * 4 + c], X4[c], v);
    const float2 sc = stb[o];
    feat[o] = leaky(fmaf(v, sc.x, sc.y), 0.2f);
  }
  for (int o = 0; o < 32; ++o){       // pe
    float v = 0.f;
#pragma unroll
    for (int c = 0; c < 10; ++c) v = fmaf(pos_w[o * 10 + c], E[c], v);
    const float2 sc = stb[32 + o];
    feat[32 + o] = leaky(fmaf(v, sc.x, sc.y), 0.2f);
  }

  float logit = 0.f;
  for (int h = 0; h < 32; ++h){
    float v = 0.f;
#pragma unroll
    for (int c = 0; c < 64; ++c) v = fmaf(att_w1[h * 64 + c], feat[c], v);
    logit = fmaf(att_w2[h], leaky(v, 0.2f), logit);
  }
  float mx = logit;
  mx = fmaxf(mx, __shfl_xor(mx, 1, 16)); mx = fmaxf(mx, __shfl_xor(mx, 2, 16));
  mx = fmaxf(mx, __shfl_xor(mx, 4, 16)); mx = fmaxf(mx, __shfl_xor(mx, 8, 16));
  const float e = expf(logit - mx);
  float den = e;
  den += __shfl_xor(den, 1, 16); den += __shfl_xor(den, 2, 16);
  den += __shfl_xor(den, 4, 16); den += __shfl_xor(den, 8, 16);
  const float att = e / den;

#pragma unroll
  for (int c = 0; c < 64; ++c){       // pooled (replicated on all 16 lanes)
    float p = feat[c] * att;
    p += __shfl_xor(p, 1, 16); p += __shfl_xor(p, 2, 16);
    p += __shfl_xor(p, 4, 16); p += __shfl_xor(p, 8, 16);
    feat[c] = p;
  }

  const float X0[4] = {cx, cy, cz, cw};
  float* outb = out + (size_t)b * 68 * Sn;
#pragma unroll
  for (int jj = 0; jj < 4; ++jj){
    const int j = k * 4 + jj;
    float f1 = 0.f;
#pragma unroll
    for (int c = 0; c < 64; ++c) f1 = fmaf(b1_w[j * 64 + c], feat[c], f1);
    float f2 = 0.f;
#pragma unroll
    for (int c = 0; c < 4; ++c) f2 = fmaf(b2_w[j * 4 + c], X0[c], f2);
    outb[(size_t)(4 + j) * Sn + sp] = leaky(f1 + f2, 0.1f);
  }
  if (k == 0){
    outb[0 * Sn + sp] = cx; outb[1 * Sn + sp] = cy;
    outb[2 * Sn + sp] = cz; outb[3 * Sn + sp] = cw;
  }
}

extern "C" void kernel_launch(void* const* d_in, const int* in_sizes, int n_in,
                              void* d_out, int out_size, void* d_ws, size_t ws_size,
                              hipStream_t stream){
  const float* x      = (const float*)d_in[0];
  const int*   perm   = (const int*)d_in[1];
  const float* pos_w  = (const float*)d_in[3];
  const float* bn2_g  = (const float*)d_in[4];
  const float* bn2_b  = (const float*)d_in[5];
  const float* conv_w = (const float*)d_in[6];
  const float* bn_g   = (const float*)d_in[7];
  const float* bn_b   = (const float*)d_in[8];
  const float* att_w1 = (const float*)d_in[9];
  const float* att_w2 = (const float*)d_in[10];
  const float* b1_w   = (const float*)d_in[11];
  const float* b2_w   = (const float*)d_in[12];
  float* out = (float*)d_out;

  char* ws = (char*)d_ws;
  int*    idx   = (int*)ws;                       // 2 MiB
  float4* pk    = (float4*)(ws + 2097152);        // 1 MiB
  uint4*  rec   = (uint4*)(ws + 3145728);         // 2 MiB (B*P*32B)
  uint4*  aq    = (uint4*)(ws + 5242880);         // 1 MiB (B*S*32B)
  float*  part  = (float*)(ws + 6291456);         // 192 KiB
  float2* stats = (float2*)(ws + 6488064);        // 2 KiB

  hipLaunchKernelGGL(k_pack,   dim3(256),            dim3(256), 0, stream, x, pk, rec);
  hipLaunchKernelGGL(k_aq,     dim3(128),            dim3(256), 0, stream, pk, perm, aq);
  hipLaunchKernelGGL(k_topk,   dim3(128, 4),         dim3(256), 0, stream, pk, rec, aq,
                     perm, idx);
  hipLaunchKernelGGL(k_stats,  dim3(ST_CHUNKS, 4),   dim3(256), 0, stream, pk, x, idx, part);
  hipLaunchKernelGGL(k_stats2, dim3(1),              dim3(640), 0, stream, part, pos_w, conv_w,
                     bn2_g, bn2_b, bn_g, bn_b, stats);
  hipLaunchKernelGGL(k_final,  dim3(512, 4),         dim3(256), 0, stream, pk, x, idx, stats,
                     conv_w, pos_w, att_w1, att_w2, b1_w, b2_w, out);
}

// Round 9
// 507.507 us; speedup vs baseline: 1.1517x; 1.1517x over previous
//
#include <hip/hip_runtime.h>
#include <math.h>

#define DEVI static __device__ __forceinline__

constexpr int Bn = 4, Cn = 4, Pn = 16384, Sn = 8192, Kn = 16;
constexpr float GN_N = 131072.0f;   // S*K per (b,channel)
constexpr int PART_STRIDE = 96;     // 79 used
constexpr int ST_CHUNKS = 128;      // k_stats grid.x
constexpr int TILE = 512;           // k_topk candidate tile
constexpr int HALF = 8192;          // candidate partition size

typedef __attribute__((ext_vector_type(8))) short s16x8;
typedef __attribute__((ext_vector_type(4))) float f32x4;

// non-contracted f32 ops (exact pd must match np's mul/add order)
DEVI float mulrn(float a, float b){ return __fmul_rn(a, b); }
DEVI float addrn(float a, float b){ return __fadd_rn(a, b); }
DEVI float subrn(float a, float b){ return __fsub_rn(a, b); }
DEVI float leaky(float v, float s){ return v >= 0.0f ? v : s * v; }

// DPP row_shr:1 == shfl_up(x,1,16) within each 16-lane quarter (DPP row).
DEVI float dpp_up1f(float x){
  int xi = __builtin_bit_cast(int, x);
  int r = __builtin_amdgcn_update_dpp(xi, xi, 0x111, 0xF, 0xF, false);
  return __builtin_bit_cast(float, r);
}
DEVI int dpp_up1i(int x){
  return __builtin_amdgcn_update_dpp(x, x, 0x111, 0xF, 0xF, false);
}
// lane (i|15) broadcast within each 16-lane quarter
DEVI float swz15(float x){
  int xi = __builtin_bit_cast(int, x);
  int r = __builtin_amdgcn_ds_swizzle(xi, 0x1FF);
  return __builtin_bit_cast(float, r);
}
// LDS anti-bank-conflict swizzle (bits1-2 ^= bits3-4; involution, block-local)
DEVI int SW(int j){ return j ^ ((j >> 2) & 6); }

// bf16 RN hi/lo split: v ~= hi + lo with |v-hi-lo| <= 2^-18|v|
DEVI void bsplit(float v, unsigned &hi, unsigned &lo){
  unsigned u = __builtin_bit_cast(unsigned, v);
  hi = (u + 0x7FFFu + ((u >> 16) & 1u)) >> 16;
  float fh = __builtin_bit_cast(float, hi << 16);
  float r = v - fh;
  unsigned u2 = __builtin_bit_cast(unsigned, r);
  lo = (u2 + 0x7FFFu + ((u2 >> 16) & 1u)) >> 16;
}

// ---------------- K1: pack coords + norm (f32) + bf16 hi/lo B-record -------
__global__ void k_pack(const float* __restrict__ x, float4* __restrict__ pk,
                       uint4* __restrict__ rec){
  int i = blockIdx.x * 256 + threadIdx.x;       // 0 .. B*P-1
  int b = i >> 14, p = i & (Pn - 1);
  const float* xb = x + (size_t)b * Cn * Pn;
  float x0 = xb[p], x1 = xb[Pn + p], x2 = xb[2 * Pn + p];
  float n = addrn(addrn(mulrn(x0, x0), mulrn(x1, x1)), mulrn(x2, x2));
  pk[i] = make_float4(x0, x1, x2, n);
  unsigned hx, lx, hy, ly, hz, lz, hw, lw;
  bsplit(x0, hx, lx); bsplit(x1, hy, ly); bsplit(x2, hz, lz); bsplit(n, hw, lw);
  unsigned nwh = hw ^ 0x8000u, nwl = lw ^ 0x8000u;   // negate bf16 (exact)
  uint4 r0 = { hx | (hy << 16), hz | (hx << 16), hy | (hz << 16), lx | (ly << 16) };
  uint4 r1 = { lz | (nwh << 16), nwl | (lx << 16), ly | (lz << 16), 0u };
  rec[i * 2] = r0; rec[i * 2 + 1] = r1;
}

// ---------------- K1b: per-query A-record (32B = 16 bf16) ------------------
__global__ void k_aq(const float4* __restrict__ pk, const int* __restrict__ perm,
                     uint4* __restrict__ aq){
  int i = blockIdx.x * 256 + threadIdx.x;       // 0 .. B*Sn-1
  int b = i >> 13;
  int q = perm[i];
  float4 sv = pk[b * Pn + q];
  float tx = 2.0f * sv.x, ty = 2.0f * sv.y, tz = 2.0f * sv.z;
  unsigned thx, tlx, thy, tly, thz, tlz;
  bsplit(tx, thx, tlx); bsplit(ty, thy, tly); bsplit(tz, thz, tlz);
  const unsigned one = 0x3F80u;
  uint4 a0 = { thx | (thy << 16), thz | (tlx << 16), tly | (tlz << 16), thx | (thy << 16) };
  uint4 a1 = { thz | (one << 16), one | (tlx << 16), tly | (tlz << 16), 0u };
  aq[i * 2] = a0; aq[i * 2 + 1] = a1;
}

// ---------------- K2: stable top-16 per (b,s) via MFMA screen --------------
// 512-thread block = 8 waves: waves 0-3 scan cands [0,8192) and waves 4-7
// scan [8192,16384) for the SAME 64 queries; in-block LDS merge at the end.
// Per wave: 16 queries (C rows), quarter h owns queries 4h..4h+3 and the
// DPP insert machinery. Screen: pipelined mfma_f32_16x16x32_bf16 with hi/lo
// split; slack 1e-2. Insert recomputes EXACT np-order pd from f32 LDS.
__launch_bounds__(512, 4)
__global__ void k_topk(const float4* __restrict__ pk, const uint4* __restrict__ rec,
                       const uint4* __restrict__ aq, const int* __restrict__ perm,
                       int* __restrict__ idx){
  __shared__ __align__(16) char smem[49184];    // 2x (lbuf 16400B + lpk 8192B)
  const int b = blockIdx.y;
  const int tid = threadIdx.x;
  const int lane = tid & 63;
  const int lane16 = lane & 15;
  const int h = lane >> 4;                      // quarter
  const int w = tid >> 6;                       // wave 0..7
  const int part = w >> 2;                      // candidate partition
  const int tid2 = tid & 255;                   // id within partition half
  const bool lane0 = (lane16 == 0);
  const unsigned long long qmask = 0xFFFFull << (h * 16);
  const int qbase = (blockIdx.x * 4 + (w & 3)) * 16;

  uint4*  lbufp = (uint4*)(smem + part * 24592);
  float4* lpkp  = (float4*)(smem + part * 24592 + 16400);

  // A-frag: lane holds A[row=lane16][k=8h..8h+7]; quarters 2,3 are zero slots.
  s16x8 afrag = (s16x8){0,0,0,0,0,0,0,0};
  if (h < 2)
    afrag = __builtin_bit_cast(s16x8, aq[(b * Sn + qbase + lane16) * 2 + h]);

  // exact query coords for this quarter's 4 queries
  float qx[4], qy[4], qz[4], qn[4];
#pragma unroll
  for (int r = 0; r < 4; ++r){
    int q = perm[b * Sn + qbase + 4 * h + r];
    float4 sv = pk[b * Pn + q];
    qx[r] = sv.x; qy[r] = sv.y; qz[r] = sv.z; qn[r] = sv.w;
  }

  float lv[4] = {-INFINITY, -INFINITY, -INFINITY, -INFINITY};
  int   li[4] = {0, 0, 0, 0};
  float T[4]  = {-INFINITY, -INFINITY, -INFINITY, -INFINITY};

  const int boff = lane16 * 2 + h;              // rec sub-index (h<2)
  const bool bvalid = (h < 2);

#define LOADB(BF, ST)                                                         \
  { const int cb2_ = (ST) * 128;                                              \
    _Pragma("unroll")                                                         \
    for (int m_ = 0; m_ < 4; ++m_){                                           \
      const int bi_ = bvalid ? SW(cb2_ + m_ * 32 + boff) : 1024;              \
      BF[m_] = __builtin_bit_cast(s16x8, lbufp[bi_]); } }

#define MFMA4(CC, BF)                                                         \
  { _Pragma("unroll")                                                         \
    for (int m_ = 0; m_ < 4; ++m_)                                            \
      CC[m_] = __builtin_amdgcn_mfma_f32_16x16x32_bf16(                       \
                 afrag, BF[m_], (f32x4){0.f,0.f,0.f,0.f}, 0, 0, 0); }

#define PROC(REG, M, CBL)                                                     \
  { unsigned long long mm = __ballot(Ca[M][REG] > T[REG]) & qmask;            \
    if (mm){                                                                  \
      do {                                                                    \
        const int src = __builtin_ctzll(mm);                                  \
        mm &= mm - 1;                                                         \
        const int lc = (CBL) + (M) * 16 + (src & 15);                         \
        const float4 cd = lpkp[lc];                                           \
        const float dot = addrn(addrn(mulrn(cd.x, qx[REG]),                   \
                                      mulrn(cd.y, qy[REG])),                  \
                                mulrn(cd.z, qz[REG]));                        \
        const float cv = subrn(subrn(mulrn(2.0f, dot), cd.w), qn[REG]);       \
        const int ci = gb0 + lc;                                              \
        const float upv = dpp_up1f(lv[REG]);                                  \
        const int   upi = dpp_up1i(li[REG]);                                  \
        const bool keep = (lv[REG] >= cv);                                    \
        const bool ins  = (!keep) && (lane0 || upv >= cv);                    \
        lv[REG] = keep ? lv[REG] : (ins ? cv : upv);                          \
        li[REG] = keep ? li[REG] : (ins ? ci : upi);                          \
      } while (mm);                                                           \
      const float tau = swz15(lv[REG]);                                       \
      T[REG] = subrn(addrn(tau, qn[REG]),                                     \
                     fmaf(fabsf(tau) + fabsf(qn[REG]), 1e-6f, 1e-2f));        \
    } }

  for (int tile = 0; tile < HALF / TILE; ++tile){
    __syncthreads();
    const int cbase = part * HALF + tile * TILE;
    const uint4* grec = rec + (size_t)(b * Pn + cbase) * 2;
    for (int j = tid2; j < TILE * 2; j += 256){
      const int dj = (j & ~31) | SW(j & 31);
      lbufp[dj] = grec[j];
    }
    const float4* gpk = pk + b * Pn + cbase;
    for (int j = tid2; j < TILE; j += 256) lpkp[j] = gpk[j];
    if (tid2 == 0) lbufp[1024] = (uint4){0u, 0u, 0u, 0u};
    __syncthreads();
    const int gb0 = cbase;

    s16x8 bf[4];
    f32x4 Ca[4], Cb[4];
    LOADB(bf, 0)
    MFMA4(Ca, bf)
#pragma unroll
    for (int st = 0; st < 8; ++st){
      if (st < 7){ LOADB(bf, st + 1) MFMA4(Cb, bf) }
      const int cbL = st * 64;
      float mxr[4];
#pragma unroll
      for (int reg = 0; reg < 4; ++reg)
        mxr[reg] = fmaxf(fmaxf(Ca[0][reg], Ca[1][reg]),
                         fmaxf(Ca[2][reg], Ca[3][reg]));
#pragma unroll
      for (int reg = 0; reg < 4; ++reg){
        if (__ballot(mxr[reg] > T[reg]) & qmask){
          PROC(reg, 0, cbL)
          PROC(reg, 1, cbL)
          PROC(reg, 2, cbL)
          PROC(reg, 3, cbL)
        }
      }
      if (st < 7){ Ca[0]=Cb[0]; Ca[1]=Cb[1]; Ca[2]=Cb[2]; Ca[3]=Cb[3]; }
    }
  }
#undef PROC
#undef MFMA4
#undef LOADB

  // ---- in-block merge of the two partition lists (exact, index-stable) ----
  __syncthreads();
  float* mval = (float*)smem;                   // [part*64 + qloc][rank]
  int*   midx = (int*)(smem + 8192);
#pragma unroll
  for (int reg = 0; reg < 4; ++reg){
    const int row = part * 64 + (w & 3) * 16 + 4 * h + reg;
    mval[row * 16 + lane16] = lv[reg];
    midx[row * 16 + lane16] = li[reg];
  }
  __syncthreads();
  if (tid < 64){
    const float* A  = mval + tid * 16;
    const float* Bv = mval + (64 + tid) * 16;
    const int*   Ai = midx + tid * 16;
    const int*   Bi = midx + (64 + tid) * 16;
    int* o = idx + ((size_t)b * Sn + blockIdx.x * 64 + tid) * 16;
    int i = 0, j = 0;
#pragma unroll
    for (int r = 0; r < 16; ++r){
      const int ic = i > 15 ? 15 : i, jc = j > 15 ? 15 : j;
      const float va = A[ic], vb = Bv[jc];
      const bool takeA = (i < 16) && (j >= 16 || va >= vb);  // ties -> partition 0
      o[r] = takeA ? Ai[ic] : Bi[jc];
      i += takeA; j += !takeA;
    }
  }
}

// scramble: x1[b,c,s',k'] = x[b,c, idx[b, (16s'+k') & 8191, (16s'+k') >> 13]]
DEVI int idxq(const int* __restrict__ idxb, int f){
  return idxb[(f & (Sn - 1)) * Kn + (f >> 13)];
}

DEVI float wred(float v){
  v += __shfl_down(v, 32); v += __shfl_down(v, 16); v += __shfl_down(v, 8);
  v += __shfl_down(v, 4);  v += __shfl_down(v, 2);  v += __shfl_down(v, 1);
  return v;
}

// ---------------- K3: GN moment accumulation ----------------
__global__ void k_stats(const float4* __restrict__ pk, const float* __restrict__ x,
                        const int* __restrict__ idx, float* __restrict__ part){
  const int b = blockIdx.y, chunk = blockIdx.x, tid = threadIdx.x;
  const int sp = chunk * 64 + (tid >> 2);
  const int kq = tid & 3;
  const int* idxb = idx + b * Sn * Kn;
  const float* xw = x + ((size_t)b * Cn + 3) * Pn;

  float M10[55], mu10[10], M4[10], mu4[4];
#pragma unroll
  for (int i = 0; i < 55; ++i) M10[i] = 0.f;
#pragma unroll
  for (int i = 0; i < 10; ++i){ mu10[i] = 0.f; M4[i] = 0.f; }
#pragma unroll
  for (int i = 0; i < 4; ++i) mu4[i] = 0.f;

  const int qc = idxq(idxb, sp * 16);
  const float4 cv = pk[b * Pn + qc];

#pragma unroll
  for (int kk = 0; kk < 4; ++kk){
    const int k = kq * 4 + kk;
    const int qn = idxq(idxb, sp * 16 + k);
    const float4 pv = pk[b * Pn + qn];
    const float pw = xw[qn];
    const float dx = subrn(pv.x, cv.x), dy = subrn(pv.y, cv.y), dz = subrn(pv.z, cv.z);
    const float temp = sqrtf(addrn(addrn(mulrn(dx, dx), mulrn(dy, dy)), mulrn(dz, dz)));
    const float E[10] = {pv.x, pv.y, pv.z, cv.x, cv.y, cv.z, dx, dy, dz, temp};
    const float X[4]  = {pv.x, pv.y, pv.z, pw};
    int c = 0;
#pragma unroll
    for (int i = 0; i < 10; ++i){
      mu10[i] += E[i];
#pragma unroll
      for (int j = i; j < 10; ++j){ M10[c] += E[i] * E[j]; ++c; }
    }
    c = 0;
#pragma unroll
    for (int i = 0; i < 4; ++i){
      mu4[i] += X[i];
#pragma unroll
      for (int j = i; j < 4; ++j){ M4[c] += X[i] * X[j]; ++c; }
    }
  }

  __shared__ float red[4][80];
  const int wid = tid >> 6, ln = tid & 63;
#pragma unroll
  for (int i = 0; i < 55; ++i){ float v = wred(M10[i]); if (ln == 0) red[wid][i] = v; }
#pragma unroll
  for (int i = 0; i < 10; ++i){ float v = wred(mu10[i]); if (ln == 0) red[wid][55 + i] = v; }
#pragma unroll
  for (int i = 0; i < 10; ++i){ float v = wred(M4[i]); if (ln == 0) red[wid][65 + i] = v; }
#pragma unroll
  for (int i = 0; i < 4; ++i){ float v = wred(mu4[i]); if (ln == 0) red[wid][75 + i] = v; }
  __syncthreads();
  if (tid < 79){
    float sum = ((red[0][tid] + red[1][tid]) + red[2][tid]) + red[3][tid];
    part[(b * ST_CHUNKS + chunk) * PART_STRIDE + tid] = sum;
  }
}

// ---------------- K4: fold moments into per-(b,ch) scale/shift ----------------
__global__ void k_stats2(const float* __restrict__ part,
                         const float* __restrict__ pos_w, const float* __restrict__ conv_w,
                         const float* __restrict__ bn2_g, const float* __restrict__ bn2_b,
                         const float* __restrict__ bn_g,  const float* __restrict__ bn_b,
                         float2* __restrict__ stats){
  __shared__ float phalf[8][80];
  __shared__ float sacc[4][80];
  const int t = threadIdx.x;
  if (t < 640){
    const int pair = t / 80, i = t % 80;      // pair = b*2 + half
    if (i < 79){
      const int bb = pair >> 1, half = pair & 1;
      float a = 0.f;
      for (int c = half * 64; c < half * 64 + 64; ++c)
        a += part[(bb * ST_CHUNKS + c) * PART_STRIDE + i];
      phalf[pair][i] = a;
    }
  }
  __syncthreads();
  if (t < 320){
    const int bb = t / 80, i = t % 80;
    if (i < 79) sacc[bb][i] = phalf[bb * 2][i] + phalf[bb * 2 + 1][i];
  }
  __syncthreads();
  if (t >= 256) return;
  const int b = t >> 6, o = t & 63;
  const float* acc = sacc[b];
  float mean, ex2, gamma, beta;
  if (o < 32){                        // xc channels: conv path, bn_g/bn_b
    const float* w = conv_w + o * 4;
    float m = 0.f, e2 = 0.f; int id = 0;
#pragma unroll
    for (int i = 0; i < 4; ++i){
      m += w[i] * acc[75 + i];
#pragma unroll
      for (int j = i; j < 4; ++j){
        float t2 = w[i] * w[j] * acc[65 + id];
        e2 += (i == j) ? t2 : 2.0f * t2; ++id;
      }
    }
    mean = m / GN_N; ex2 = e2 / GN_N; gamma = bn_g[o]; beta = bn_b[o];
  } else {                            // pe channels: pos path, bn2_g/bn2_b
    const float* w = pos_w + (o - 32) * 10;
    float m = 0.f, e2 = 0.f; int id = 0;
#pragma unroll
    for (int i = 0; i < 10; ++i){
      m += w[i] * acc[55 + i];
#pragma unroll
      for (int j = i; j < 10; ++j){
        float t2 = w[i] * w[j] * acc[id];
        e2 += (i == j) ? t2 : 2.0f * t2; ++id;
      }
    }
    mean = m / GN_N; ex2 = e2 / GN_N; gamma = bn2_g[o - 32]; beta = bn2_b[o - 32];
  }
  const float var = fmaxf(ex2 - mean * mean, 0.f);
  const float rstd = 1.0f / sqrtf(var + 1e-5f);
  const float scale = rstd * gamma;
  stats[b * 64 + o] = make_float2(scale, beta - mean * scale);
}

// ---------------- K5: fused features + attention + output ----------------
__global__ void k_final(const float4* __restrict__ pk, const float* __restrict__ x,
                        const int* __restrict__ idx, const float2* __restrict__ stats,
                        const float* __restrict__ conv_w, const float* __restrict__ pos_w,
                        const float* __restrict__ att_w1, const float* __restrict__ att_w2,
                        const float* __restrict__ b1_w, const float* __restrict__ b2_w,
                        float* __restrict__ out){
  const int b = blockIdx.y;
  const int tid = threadIdx.x;
  const int k = tid & 15;
  const int sp = blockIdx.x * 16 + (tid >> 4);
  const int* idxb = idx + b * Sn * Kn;
  const float* xw = x + ((size_t)b * Cn + 3) * Pn;

  const int qn = idxq(idxb, sp * 16 + k);
  const float4 pv = pk[b * Pn + qn];
  const float pw = xw[qn];
  const float cx = __shfl(pv.x, 0, 16), cy = __shfl(pv.y, 0, 16);
  const float cz = __shfl(pv.z, 0, 16), cw = __shfl(pw, 0, 16);
  const float dx = subrn(pv.x, cx), dy = subrn(pv.y, cy), dz = subrn(pv.z, cz);
  const float temp = sqrtf(addrn(addrn(mulrn(dx, dx), mulrn(dy, dy)), mulrn(dz, dz)));
  const float E[10]  = {pv.x, pv.y, pv.z, cx, cy, cz, dx, dy, dz, temp};
  const float X4[4]  = {pv.x, pv.y, pv.z, pw};
  const float2* stb = stats + b * 64;

  float feat[64];
  for (int o = 0; o < 32; ++o){       // xc
    float v = 0.f;
#pragma unroll
    for (int c = 0; c < 4; ++c) v = fmaf(conv_w[o * 4 + c], X4[c], v);
    const float2 sc = stb[o];
    feat[o] = leaky(fmaf(v, sc.x, sc.y), 0.2f);
  }
  for (int o = 0; o < 32; ++o){       // pe
    float v = 0.f;
#pragma unroll
    for (int c = 0; c < 10; ++c) v = fmaf(pos_w[o * 10 + c], E[c], v);
    const float2 sc = stb[32 + o];
    feat[32 + o] = leaky(fmaf(v, sc.x, sc.y), 0.2f);
  }

  float logit = 0.f;
  for (int h = 0; h < 32; ++h){
    float v = 0.f;
#pragma unroll
    for (int c = 0; c < 64; ++c) v = fmaf(att_w1[h * 64 + c], feat[c], v);
    logit = fmaf(att_w2[h], leaky(v, 0.2f), logit);
  }
  float mx = logit;
  mx = fmaxf(mx, __shfl_xor(mx, 1, 16)); mx = fmaxf(mx, __shfl_xor(mx, 2, 16));
  mx = fmaxf(mx, __shfl_xor(mx, 4, 16)); mx = fmaxf(mx, __shfl_xor(mx, 8, 16));
  const float e = expf(logit - mx);
  float den = e;
  den += __shfl_xor(den, 1, 16); den += __shfl_xor(den, 2, 16);
  den += __shfl_xor(den, 4, 16); den += __shfl_xor(den, 8, 16);
  const float att = e / den;

#pragma unroll
  for (int c = 0; c < 64; ++c){       // pooled (replicated on all 16 lanes)
    float p = feat[c] * att;
    p += __shfl_xor(p, 1, 16); p += __shfl_xor(p, 2, 16);
    p += __shfl_xor(p, 4, 16); p += __shfl_xor(p, 8, 16);
    feat[c] = p;
  }

  const float X0[4] = {cx, cy, cz, cw};
  float* outb = out + (size_t)b * 68 * Sn;
#pragma unroll
  for (int jj = 0; jj < 4; ++jj){
    const int j = k * 4 + jj;
    float f1 = 0.f;
#pragma unroll
    for (int c = 0; c < 64; ++c) f1 = fmaf(b1_w[j * 64 + c], feat[c], f1);
    float f2 = 0.f;
#pragma unroll
    for (int c = 0; c < 4; ++c) f2 = fmaf(b2_w[j * 4 + c], X0[c], f2);
    outb[(size_t)(4 + j) * Sn + sp] = leaky(f1 + f2, 0.1f);
  }
  if (k == 0){
    outb[0 * Sn + sp] = cx; outb[1 * Sn + sp] = cy;
    outb[2 * Sn + sp] = cz; outb[3 * Sn + sp] = cw;
  }
}

extern "C" void kernel_launch(void* const* d_in, const int* in_sizes, int n_in,
                              void* d_out, int out_size, void* d_ws, size_t ws_size,
                              hipStream_t stream){
  const float* x      = (const float*)d_in[0];
  const int*   perm   = (const int*)d_in[1];
  const float* pos_w  = (const float*)d_in[3];
  const float* bn2_g  = (const float*)d_in[4];
  const float* bn2_b  = (const float*)d_in[5];
  const float* conv_w = (const float*)d_in[6];
  const float* bn_g   = (const float*)d_in[7];
  const float* bn_b   = (const float*)d_in[8];
  const float* att_w1 = (const float*)d_in[9];
  const float* att_w2 = (const float*)d_in[10];
  const float* b1_w   = (const float*)d_in[11];
  const float* b2_w   = (const float*)d_in[12];
  float* out = (float*)d_out;

  char* ws = (char*)d_ws;
  int*    idx   = (int*)ws;                       // 2 MiB
  float4* pk    = (float4*)(ws + 2097152);        // 1 MiB
  uint4*  rec   = (uint4*)(ws + 3145728);         // 2 MiB (B*P*32B)
  uint4*  aq    = (uint4*)(ws + 5242880);         // 1 MiB (B*S*32B)
  float*  part  = (float*)(ws + 6291456);         // 192 KiB
  float2* stats = (float2*)(ws + 6488064);        // 2 KiB

  hipLaunchKernelGGL(k_pack,   dim3(256),            dim3(256), 0, stream, x, pk, rec);
  hipLaunchKernelGGL(k_aq,     dim3(128),            dim3(256), 0, stream, pk, perm, aq);
  hipLaunchKernelGGL(k_topk,   dim3(128, 4),         dim3(512), 0, stream, pk, rec, aq,
                     perm, idx);
  hipLaunchKernelGGL(k_stats,  dim3(ST_CHUNKS, 4),   dim3(256), 0, stream, pk, x, idx, part);
  hipLaunchKernelGGL(k_stats2, dim3(1),              dim3(640), 0, stream, part, pos_w, conv_w,
                     bn2_g, bn2_b, bn_g, bn_b, stats);
  hipLaunchKernelGGL(k_final,  dim3(512, 4),         dim3(256), 0, stream, pk, x, idx, stats,
                     conv_w, pos_w, att_w1, att_w2, b1_w, b2_w, out);
}